// Round 5
// baseline (396.143 us; speedup 1.0000x reference)
//
#include <hip/hip_runtime.h>
#include <cstdint>
#include <cstddef>

#define N_NODES 8192
#define DIN 128
#define CAP 128          // max stored nnz per row (mean ~33, huge sigma margin)
#define EPSF 1e-7f

typedef unsigned short u16;
typedef unsigned int u32;

// ---------------- Kernel 1: CSR build + degree norm (one wave per row) ----
// adj entries are exactly 0.0f or 1.0f. Each wave scans one 8192-float row
// with float4 loads, ballot-compacts nonzero column indices, and writes
// D[row] = 1/sqrt(1+deg). The scan is ROTATED by (row & 31) iterations:
// rows are 32KB-aligned and waves advance in lockstep, so without rotation
// all resident waves hit the same 1KB offset phase simultaneously (power-of-2
// stride channel convoy). Rotation spreads instantaneous addresses over all
// 32 phases. Column order within a row becomes rotated, which is fine: the
// downstream aggregation is a commutative sum over the column set.
__global__ __launch_bounds__(256) void k_build(const float4* __restrict__ adj,
                                               u16* __restrict__ cols,
                                               int* __restrict__ counts,
                                               float* __restrict__ Dv) {
    const int lane = threadIdx.x & 63;
    const int row  = blockIdx.x * 4 + (threadIdx.x >> 6);
    const float4* rp = adj + (size_t)row * (N_NODES / 4);
    u16* cl = cols + (size_t)row * CAP;
    const unsigned long long lt_mask = (1ULL << lane) - 1ULL;
    const int s = row & 31;              // per-row phase stagger

    int base = 0;
#pragma unroll 8
    for (int ii = 0; ii < N_NODES / 256; ++ii) {
        const int it = (ii + s) & 31;
        float4 v = rp[it * 64 + lane];
        int cb = it * 256 + lane * 4;
        {
            bool nz = (v.x != 0.0f);
            unsigned long long m = __ballot(nz);
            if (nz) { int p = base + __popcll(m & lt_mask); if (p < CAP) cl[p] = (u16)(cb + 0); }
            base += __popcll(m);
        }
        {
            bool nz = (v.y != 0.0f);
            unsigned long long m = __ballot(nz);
            if (nz) { int p = base + __popcll(m & lt_mask); if (p < CAP) cl[p] = (u16)(cb + 1); }
            base += __popcll(m);
        }
        {
            bool nz = (v.z != 0.0f);
            unsigned long long m = __ballot(nz);
            if (nz) { int p = base + __popcll(m & lt_mask); if (p < CAP) cl[p] = (u16)(cb + 2); }
            base += __popcll(m);
        }
        {
            bool nz = (v.w != 0.0f);
            unsigned long long m = __ballot(nz);
            if (nz) { int p = base + __popcll(m & lt_mask); if (p < CAP) cl[p] = (u16)(cb + 3); }
            base += __popcll(m);
        }
    }
    if (lane == 0) {
        counts[row] = base;
        Dv[row] = 1.0f / sqrtf(1.0f + (float)base);
    }
}

__device__ __forceinline__ float waveSum(float v) {
#pragma unroll
    for (int m = 32; m >= 1; m >>= 1) v += __shfl_xor(v, m, 64);
    return v;
}

// ---------------- Kernel 2: fused aggregate + mobius/logmap0 + FC + expmap0
// 256 threads = 4 waves; one wave per row for aggregation (lane owns a float2
// of feature dims; reductions are barrier-free wave butterflies; LDS staging
// is within-wave and execution-ordered). Then one barrier and an FC pass with
// coalesced W loads amortized over 4 rows. Only 2 __syncthreads total.
__global__ __launch_bounds__(256) void k_fused(const float* __restrict__ x,
                                               const float* __restrict__ Dv,
                                               const u16* __restrict__ cols,
                                               const int* __restrict__ counts,
                                               const float* __restrict__ W,
                                               const float* __restrict__ b,
                                               float* __restrict__ out) {
    __shared__ u16   colsL[4][CAP];
    __shared__ float djL[4][CAP];
    __shared__ float uL[4][DIN];
    __shared__ float red[8];

    const int tid = threadIdx.x;
    const int w   = tid >> 6;            // wave = row slot 0..3
    const int l   = tid & 63;            // lane
    const int row0 = blockIdx.x * 4;
    const int row  = row0 + w;
    const float2* x2 = (const float2*)x;

    int c = counts[row];
    if (c > CAP) c = CAP;

    // Stage this row's column list (64 dwords = 128 u16) and D_j (within-wave).
    ((u32*)colsL[w])[l] = ((const u32*)(cols + (size_t)row * CAP))[l];
    {
        int k0 = 2 * l, k1 = 2 * l + 1;
        int j0 = colsL[w][k0], j1 = colsL[w][k1];
        djL[w][k0] = (k0 < c) ? Dv[j0] : 0.0f;
        djL[w][k1] = (k1 < c) ? Dv[j1] : 0.0f;
    }
    const float2 xi = x2[(size_t)row * 64 + l];
    const float  Di = Dv[row];

    // acc = D_i x_i + sum_j D_j x_j ; sumw = D_i + sum_j D_j  (lane: 2 dims)
    float ax = Di * xi.x, ay = Di * xi.y;
    float sumw = Di;
#pragma unroll 4
    for (int k = 0; k < c; ++k) {
        int   j  = colsL[w][k];
        float dj = djL[w][k];
        sumw += dj;
        float2 xj = x2[(size_t)j * 64 + l];
        ax = fmaf(dj, xj.x, ax);
        ay = fmaf(dj, xj.y, ay);
    }

    // gamma from ||x_i||^2 (degree factors cancel analytically)
    float r2 = waveSum(fmaf(xi.x, xi.x, xi.y * xi.y));
    float gamma = fminf(2.0f / (1.0f - r2), 1e7f);
    float sg = gamma / ((gamma - 1.0f) * sumw);
    ax *= sg; ay *= sg;                               // aggr[i, dims]

    // mobius scalar-mul(0.5) fused with logmap0 (||m|| known analytically)
    float n2 = waveSum(fmaf(ax, ax, ay * ay));
    float n  = sqrtf(n2);
    float nsafe = fminf(fmaxf(n, EPSF), 1.0f - EPSF);
    float t  = tanhf(0.5f * atanhf(nsafe));
    float nm = t * (n / nsafe);                       // ||mobius(0.5,aggr)||
    float nmsafe = fminf(fmaxf(nm, EPSF), 1.0f - EPSF);
    float us = (atanhf(nmsafe) / nmsafe) * (t / nsafe);
    ((float2*)uL[w])[l] = make_float2(us * ax, us * ay);

    __syncthreads();   // uL rows visible to all waves

    // FC halves: h=0 (waves 0,1) -> rows 0,1 ; h=1 -> rows 2,3.
    const int h = tid >> 7;
    const int d = tid & 127;
    const float bd = b[d];
    float a0 = bd, a1 = bd;                           // rows 2h, 2h+1
    const float* Wc = W + d;
    const float* u0 = uL[2 * h];
    const float* u1 = uL[2 * h + 1];
#pragma unroll 8
    for (int k = 0; k < DIN; ++k) {
        float wkd = Wc[(size_t)k * DIN];
        a0 = fmaf(u0[k], wkd, a0);
        a1 = fmaf(u1[k], wkd, a1);
    }

    // relu + expmap0; row norm = two 64-lane partials combined through LDS.
    float y0 = fmaxf(a0, 0.0f), y1 = fmaxf(a1, 0.0f);
    float s0 = waveSum(y0 * y0);
    float s1 = waveSum(y1 * y1);
    if (l == 0) { red[w * 2] = s0; red[w * 2 + 1] = s1; }
    __syncthreads();
    float ss0 = red[4 * h + 0] + red[4 * h + 2];      // row 2h
    float ss1 = red[4 * h + 1] + red[4 * h + 3];      // row 2h+1
    float ns0 = fmaxf(sqrtf(ss0), EPSF);
    float ns1 = fmaxf(sqrtf(ss1), EPSF);
    float sc0 = tanhf(ns0) / ns0;
    float sc1 = tanhf(ns1) / ns1;
    out[(size_t)(row0 + 2 * h) * DIN + d]     = y0 * sc0;
    out[(size_t)(row0 + 2 * h + 1) * DIN + d] = y1 * sc1;
}

// ---------------- launch ----------------
extern "C" void kernel_launch(void* const* d_in, const int* in_sizes, int n_in,
                              void* d_out, int out_size, void* d_ws, size_t ws_size,
                              hipStream_t stream) {
    const float* x   = (const float*)d_in[0];   // [8192,128]
    const float* adj = (const float*)d_in[1];   // [8192,8192]
    const float* W   = (const float*)d_in[2];   // [128,128]
    const float* b   = (const float*)d_in[3];   // [128]
    float* out = (float*)d_out;

    char* ws = (char*)d_ws;
    int*   counts = (int*)ws;                              // 32 KB
    float* Dv     = (float*)(ws + 32768);                  // 32 KB
    u16*   cols   = (u16*)(ws + 65536);                    // 2 MB

    hipLaunchKernelGGL(k_build, dim3(N_NODES / 4), dim3(256), 0, stream,
                       (const float4*)adj, cols, counts, Dv);
    hipLaunchKernelGGL(k_fused, dim3(N_NODES / 4), dim3(256), 0, stream,
                       x, Dv, cols, counts, W, b, out);
}

// Round 6
// 367.903 us; speedup vs baseline: 1.0768x; 1.0768x over previous
//
#include <hip/hip_runtime.h>
#include <cstdint>
#include <cstddef>

#define N_NODES 8192
#define DIN 128
#define CAP 128          // max stored nnz per row (mean ~33, huge sigma margin)
#define EPSF 1e-7f

typedef unsigned short u16;
typedef unsigned int u32;
typedef u32 nuint4 __attribute__((ext_vector_type(4)));   // nontemporal-ok

// ---------------- Kernel 1: CSR build + degree norm (one wave per row) ----
// adj entries are exactly 0.0f or 1.0f (bit patterns 0 / 0x3F800000).
// Nonzeros are RARE (~33 per 8192-col row, E~2 per 2KB chunk), so the scan is
// detection-optimized: per 2KB chunk each lane OR-reduces its 32B, one
// compare + one ballot decides if ANY lane saw a nonzero; the decode/store
// path is exec-masked and usually skipped via s_cbranch_execz. Compaction
// offsets come from a per-wave LDS atomic counter -- column ORDER within a
// row is arbitrary, which is fine: downstream aggregation is a commutative
// sum over the column set. Loads are nontemporal (read-once 256MB stream;
// don't evict x/W/cols from L2).
__global__ __launch_bounds__(256) void k_build(const nuint4* __restrict__ adj,
                                               u16* __restrict__ cols,
                                               int* __restrict__ counts,
                                               float* __restrict__ Dv) {
    __shared__ int cnt[4];
    const int lane = threadIdx.x & 63;
    const int w    = threadIdx.x >> 6;
    const int row  = blockIdx.x * 4 + w;
    if (lane == 0) cnt[w] = 0;           // within-wave LDS order: no barrier
    const nuint4* rp = adj + (size_t)row * (N_NODES / 4);
    u16* cl = cols + (size_t)row * CAP;

#pragma unroll 2
    for (int it = 0; it < 16; ++it) {
        // two dense 1KB wave-loads: lanes 0..63 x 16B contiguous, twice
        nuint4 a = __builtin_nontemporal_load(&rp[it * 128 + lane]);
        nuint4 b = __builtin_nontemporal_load(&rp[it * 128 + 64 + lane]);
        u32 oa = (a.x | a.y) | (a.z | a.w);
        u32 ob = (b.x | b.y) | (b.z | b.w);
        if (__ballot((oa | ob) != 0)) {          // wave-uniform: ~64% taken
            if ((oa | ob) != 0) {                // divergent: ~1-2 lanes
                // count via float adds (words are exactly 0.0f or 1.0f)
                float cf = ((__uint_as_float(a.x) + __uint_as_float(a.y)) +
                            (__uint_as_float(a.z) + __uint_as_float(a.w))) +
                           ((__uint_as_float(b.x) + __uint_as_float(b.y)) +
                            (__uint_as_float(b.z) + __uint_as_float(b.w)));
                int c = (int)cf;
                int p = atomicAdd(&cnt[w], c);   // claim positions (LDS)
                int ca = it * 512 + 4 * lane;    // a covers cols ca..ca+3
                int cb = ca + 256;               // b covers cols cb..cb+3
                u32 ws8[8] = {a.x, a.y, a.z, a.w, b.x, b.y, b.z, b.w};
#pragma unroll
                for (int k = 0; k < 8; ++k)
                    if (ws8[k]) {                // execz-skipped when no lane set
                        if (p < CAP) cl[p] = (u16)((k < 4 ? ca : cb - 4) + k);
                        ++p;
                    }
            }
        }
    }
    int deg = cnt[w];                    // same-wave atomics are ordered
    if (lane == 0) {
        counts[row] = deg;
        Dv[row] = 1.0f / sqrtf(1.0f + (float)deg);
    }
}

__device__ __forceinline__ float waveSum(float v) {
#pragma unroll
    for (int m = 32; m >= 1; m >>= 1) v += __shfl_xor(v, m, 64);
    return v;
}

// ---------------- Kernel 2: fused aggregate + mobius/logmap0 + FC + expmap0
// 256 threads = 4 waves; one wave per row for aggregation (lane owns a float2
// of feature dims; reductions are barrier-free wave butterflies; LDS staging
// is within-wave and execution-ordered). Then one barrier and an FC pass with
// coalesced W loads amortized over 4 rows. Only 2 __syncthreads total.
__global__ __launch_bounds__(256) void k_fused(const float* __restrict__ x,
                                               const float* __restrict__ Dv,
                                               const u16* __restrict__ cols,
                                               const int* __restrict__ counts,
                                               const float* __restrict__ W,
                                               const float* __restrict__ b,
                                               float* __restrict__ out) {
    __shared__ u16   colsL[4][CAP];
    __shared__ float djL[4][CAP];
    __shared__ float uL[4][DIN];
    __shared__ float red[8];

    const int tid = threadIdx.x;
    const int w   = tid >> 6;            // wave = row slot 0..3
    const int l   = tid & 63;            // lane
    const int row0 = blockIdx.x * 4;
    const int row  = row0 + w;
    const float2* x2 = (const float2*)x;

    int c = counts[row];
    if (c > CAP) c = CAP;

    // Stage this row's column list (64 dwords = 128 u16) and D_j (within-wave).
    ((u32*)colsL[w])[l] = ((const u32*)(cols + (size_t)row * CAP))[l];
    {
        int k0 = 2 * l, k1 = 2 * l + 1;
        int j0 = (k0 < c) ? colsL[w][k0] : 0;   // select BEFORE load (poison-safe)
        int j1 = (k1 < c) ? colsL[w][k1] : 0;
        djL[w][k0] = (k0 < c) ? Dv[j0] : 0.0f;
        djL[w][k1] = (k1 < c) ? Dv[j1] : 0.0f;
    }
    const float2 xi = x2[(size_t)row * 64 + l];
    const float  Di = Dv[row];

    // acc = D_i x_i + sum_j D_j x_j ; sumw = D_i + sum_j D_j  (lane: 2 dims)
    float ax = Di * xi.x, ay = Di * xi.y;
    float sumw = Di;
#pragma unroll 4
    for (int k = 0; k < c; ++k) {
        int   j  = colsL[w][k];
        float dj = djL[w][k];
        sumw += dj;
        float2 xj = x2[(size_t)j * 64 + l];
        ax = fmaf(dj, xj.x, ax);
        ay = fmaf(dj, xj.y, ay);
    }

    // gamma from ||x_i||^2 (degree factors cancel analytically)
    float r2 = waveSum(fmaf(xi.x, xi.x, xi.y * xi.y));
    float gamma = fminf(2.0f / (1.0f - r2), 1e7f);
    float sg = gamma / ((gamma - 1.0f) * sumw);
    ax *= sg; ay *= sg;                               // aggr[i, dims]

    // mobius scalar-mul(0.5) fused with logmap0 (||m|| known analytically)
    float n2 = waveSum(fmaf(ax, ax, ay * ay));
    float n  = sqrtf(n2);
    float nsafe = fminf(fmaxf(n, EPSF), 1.0f - EPSF);
    float t  = tanhf(0.5f * atanhf(nsafe));
    float nm = t * (n / nsafe);                       // ||mobius(0.5,aggr)||
    float nmsafe = fminf(fmaxf(nm, EPSF), 1.0f - EPSF);
    float us = (atanhf(nmsafe) / nmsafe) * (t / nsafe);
    ((float2*)uL[w])[l] = make_float2(us * ax, us * ay);

    __syncthreads();   // uL rows visible to all waves

    // FC halves: h=0 (waves 0,1) -> rows 0,1 ; h=1 -> rows 2,3.
    const int h = tid >> 7;
    const int d = tid & 127;
    const float bd = b[d];
    float a0 = bd, a1 = bd;                           // rows 2h, 2h+1
    const float* Wc = W + d;
    const float* u0 = uL[2 * h];
    const float* u1 = uL[2 * h + 1];
#pragma unroll 8
    for (int k = 0; k < DIN; ++k) {
        float wkd = Wc[(size_t)k * DIN];
        a0 = fmaf(u0[k], wkd, a0);
        a1 = fmaf(u1[k], wkd, a1);
    }

    // relu + expmap0; row norm = two 64-lane partials combined through LDS.
    float y0 = fmaxf(a0, 0.0f), y1 = fmaxf(a1, 0.0f);
    float s0 = waveSum(y0 * y0);
    float s1 = waveSum(y1 * y1);
    if (l == 0) { red[w * 2] = s0; red[w * 2 + 1] = s1; }
    __syncthreads();
    float ss0 = red[4 * h + 0] + red[4 * h + 2];      // row 2h
    float ss1 = red[4 * h + 1] + red[4 * h + 3];      // row 2h+1
    float ns0 = fmaxf(sqrtf(ss0), EPSF);
    float ns1 = fmaxf(sqrtf(ss1), EPSF);
    float sc0 = tanhf(ns0) / ns0;
    float sc1 = tanhf(ns1) / ns1;
    out[(size_t)(row0 + 2 * h) * DIN + d]     = y0 * sc0;
    out[(size_t)(row0 + 2 * h + 1) * DIN + d] = y1 * sc1;
}

// ---------------- launch ----------------
extern "C" void kernel_launch(void* const* d_in, const int* in_sizes, int n_in,
                              void* d_out, int out_size, void* d_ws, size_t ws_size,
                              hipStream_t stream) {
    const float* x   = (const float*)d_in[0];   // [8192,128]
    const float* adj = (const float*)d_in[1];   // [8192,8192]
    const float* W   = (const float*)d_in[2];   // [128,128]
    const float* b   = (const float*)d_in[3];   // [128]
    float* out = (float*)d_out;

    char* ws = (char*)d_ws;
    int*   counts = (int*)ws;                              // 32 KB
    float* Dv     = (float*)(ws + 32768);                  // 32 KB
    u16*   cols   = (u16*)(ws + 65536);                    // 2 MB

    hipLaunchKernelGGL(k_build, dim3(N_NODES / 4), dim3(256), 0, stream,
                       (const nuint4*)adj, cols, counts, Dv);
    hipLaunchKernelGGL(k_fused, dim3(N_NODES / 4), dim3(256), 0, stream,
                       x, Dv, cols, counts, W, b, out);
}